// Round 3
// baseline (197.691 us; speedup 1.0000x reference)
//
#include <hip/hip_runtime.h>
#include <math.h>

#define LSEQ 512
#define NA 20
#define NCH 8

// ---------------------------------------------------------------------------
// wf_vt_kernel (adjoint formulation): the 9-layer conv3(pad1)+avgpool2 pyramid
// is a linear map A: R^512 -> R^8.  Row r of A (= Wf[r][:]) is computed by ONE
// adjoint pass from e_r: repeatedly unpool (gz[k] = 0.5*g[k>>1]) and transposed
// 3-tap conv, lengths 1 -> 2 -> ... -> 256 -> 512.  ~0.9 MFLOP total.
//   backward step (input len P, weights w[co][ci][0..2]):
//     out[ci][2p]   = 0.5 * sum_co( (w0+w1)*g[co][p] + w2*g[co][p-1] )
//     out[ci][2p+1] = 0.5 * sum_co( (w1+w2)*g[co][p] + w0*g[co][p+1] )
// Blocks 0..7: row r.  Block 8: vtn (400 entries).  wf layout: [c][s], stride 512.
// ---------------------------------------------------------------------------
__global__ __launch_bounds__(256) void wf_vt_kernel(
    const float* __restrict__ w0,   // [8*3]
    const float* __restrict__ wsg,  // [8*8*8*3]  ws[li][co][ci][j]
    const float* __restrict__ lpm,
    const float* __restrict__ pm,
    float* __restrict__ wf,         // [8*512]
    float* __restrict__ vtn)        // [400]
{
    const int t = threadIdx.x;

    if (blockIdx.x == NCH) {
        for (int o = t; o < NA * NA; o += 256) {
            int j = o / NA, a = o % NA;
            float v = 0.f;
            if (a > j && a <= NA - 2)
                v += fminf(fmaxf(lpm[j * NA + a], 0.001f), 1.0f) * pm[j * NA + a];
            if (a < j)
                v += fminf(fmaxf(lpm[a * NA + j], 0.001f), 1.0f) * pm[a * NA + j];
            vtn[o] = v;
        }
        return;
    }

    const int r = blockIdx.x;  // output channel row of Wf

    __shared__ float gA[NCH * 256];   // [co][p], stride 256
    __shared__ float gB[NCH * 256];
    __shared__ float4 s_e[NCH * NCH]; // [co][ci] -> (w0+w1, w2, w1+w2, w0)

    if (t < NCH) gA[t * 256] = (t == r) ? 1.f : 0.f;
    __syncthreads();

    int P = 1;  // current grad length (== 1 << step)
    for (int step = 0; step < 8; ++step) {
        const int li = 7 - step;  // ws layer index, backward order
        if (t < 64) {
            const int co = t >> 3, ci = t & 7;
            const float* wp = wsg + li * 192 + co * 24 + ci * 3;
            const float a0 = wp[0], a1 = wp[1], a2 = wp[2];
            s_e[co * 8 + ci] = make_float4(a0 + a1, a2, a1 + a2, a0);
        }
        __syncthreads();
        const float* gi = (step & 1) ? gB : gA;
        float* go = (step & 1) ? gA : gB;
        for (int it = t; it < NCH * P; it += 256) {
            const int ci = it >> step;     // P == 1<<step
            const int p = it & (P - 1);
            float accE = 0.f, accO = 0.f;
#pragma unroll
            for (int co = 0; co < NCH; ++co) {
                const float g0 = gi[co * 256 + p];
                const float gm = (p > 0) ? gi[co * 256 + p - 1] : 0.f;
                const float gp = (p + 1 < P) ? gi[co * 256 + p + 1] : 0.f;
                const float4 e = s_e[co * 8 + ci];
                accE += e.x * g0 + e.y * gm;
                accO += e.z * g0 + e.w * gp;
            }
            *(float2*)(go + ci * 256 + 2 * p) = make_float2(0.5f * accE, 0.5f * accO);
        }
        __syncthreads();
        P <<= 1;
    }

    // P == 256; final state sits in gA.  Backward through layer 0 -> wf row r.
    {
        const int p = t;  // 0..255, produces output positions 2p, 2p+1
        float accE = 0.f, accO = 0.f;
#pragma unroll
        for (int co = 0; co < NCH; ++co) {
            const float g0 = gA[co * 256 + p];
            const float gm = (p > 0) ? gA[co * 256 + p - 1] : 0.f;
            const float gp = (p < 255) ? gA[co * 256 + p + 1] : 0.f;
            const float q0 = w0[co * 3 + 0], q1 = w0[co * 3 + 1], q2 = w0[co * 3 + 2];
            accE += (q0 + q1) * g0 + q2 * gm;
            accO += (q1 + q2) * g0 + q0 * gp;
        }
        *(float2*)(wf + r * 512 + 2 * p) = make_float2(0.5f * accE, 0.5f * accO);
    }
}

// ---------------------------------------------------------------------------
// main_kernel: one block per b.  No LDS atomics anywhere.
// R2 restructure: half-split column space so s_h is [20][256] (20.5 KB) and
// total LDS = 25.2 KB -> 4 blocks/CU resident (grid is exactly 4/CU).
// R3 fix: the half loop MUST be fully unrolled — with runtime `half`, wr[k]
// was runtime-indexed and the whole wr[4] array spilled to scratch
// (rocprof R2: WRITE_SIZE 219MB, VALUBusy 0.05%, 111us).  rule #20.
//  phase 0: load Wf strips into registers; stage vtn; idx from global x
//  phase 1 (per half): dense h build, verified scatter logic unchanged
//  phase 2 (per half): acc[a] += dot over this half's two 128-col groups
//  reduce: shfl seg-reduce + cross-wave partials (unchanged)
// ---------------------------------------------------------------------------
__global__ __launch_bounds__(256, 4) void main_kernel(
    const float* __restrict__ x,      // [B,L,A]
    const float* __restrict__ vtn,    // [400]
    const float* __restrict__ g_std,  // [1]
    const float* __restrict__ wf,     // [8*512]
    float* __restrict__ out)          // [B*160]
{
    const int b = blockIdx.x;
    const int t = threadIdx.x;
    const int c = t & 7;       // channel
    const int seg = t >> 3;    // 0..31: owns s = seg*4 + 128k + i
    const int w = t >> 6;
    const int lane = t & 63;

    __shared__ __align__(16) float s_h[NA * 256];   // 20480B
    __shared__ __align__(16) float s_vtn[NA * NA];  // 1600B
    __shared__ float s_part[4 * NA * NCH];          // 2560B
    __shared__ unsigned char s_idx[LSEQ];           // 512B

    // ---- phase 0: weights -> registers, vtn -> LDS, idx from global ----
    float4 wr[4];
#pragma unroll
    for (int k = 0; k < 4; ++k)
        wr[k] = *(const float4*)(wf + c * 512 + seg * 4 + 128 * k);

    if (t < NA * NA / 4) ((float4*)s_vtn)[t] = ((const float4*)vtn)[t];

    const float4* xb = (const float4*)(x + (size_t)b * LSEQ * NA);
#pragma unroll
    for (int rep = 0; rep < 2; ++rep) {
        int s = t + rep * 256;
        int id = 255;
#pragma unroll
        for (int q = 0; q < 5; ++q) {
            float4 v = xb[s * 5 + q];
            if (v.x > .5f) id = 4 * q + 0;
            if (v.y > .5f) id = 4 * q + 1;
            if (v.z > .5f) id = 4 * q + 2;
            if (v.w > .5f) id = 4 * q + 3;
        }
        s_idx[s] = (unsigned char)id;
    }
    __syncthreads();

    const float stdv = g_std[0];
    const float inv2s2 = 1.f / (2.f * stdv * stdv);
    const float vks[3] = {__expf(-1.f * inv2s2), __expf(-4.f * inv2s2), __expf(-9.f * inv2s2)};

    float acc[NA];
#pragma unroll
    for (int a = 0; a < NA; ++a) acc[a] = 0.f;

#pragma unroll
    for (int half = 0; half < 2; ++half) {
        // ---- phase 1: dense h build for columns [256*half, 256*half+256) ----
        {
            const int s = 256 * half + t;   // this thread's column (global index)
            const int ai = s_idx[s];
            const bool valid = ai < NA;
#pragma unroll
            for (int a = 0; a < NA; ++a) {
                float v = valid ? (s_vtn[ai * NA + a] + (a == ai ? 1.f : 0.f)) : 0.f;
                s_h[a * 256 + t] = v;
            }
#pragma unroll
            for (int k = 1; k <= 3; ++k) {
                const float add = vks[k - 1];
                if (s == LSEQ - 1) {
                    for (int u = LSEQ - 1 - k; u <= LSEQ - 1; ++u) {
                        int tg = s_idx[u];
                        if (tg < NA)
                            s_h[tg * 256 + t] =
                                (valid ? s_vtn[ai * NA + tg] + (tg == ai ? 1.f : 0.f) : 0.f) + add;
                    }
                } else if (s >= k) {
                    int tg = s_idx[s - k];
                    if (tg < NA)
                        s_h[tg * 256 + t] =
                            (valid ? s_vtn[ai * NA + tg] + (tg == ai ? 1.f : 0.f) : 0.f) + add;
                }
                if (s == 0) {
                    for (int u = 0; u <= k; ++u) {
                        int tg = s_idx[u];
                        if (tg < NA)
                            s_h[tg * 256 + t] =
                                (valid ? s_vtn[ai * NA + tg] + (tg == ai ? 1.f : 0.f) : 0.f) + add;
                    }
                } else if (s + k < LSEQ) {
                    int tg = s_idx[s + k];
                    if (tg < NA)
                        s_h[tg * 256 + t] =
                            (valid ? s_vtn[ai * NA + tg] + (tg == ai ? 1.f : 0.f) : 0.f) + add;
                }
            }
        }
        __syncthreads();

        // ---- phase 2: accumulate this half's two 128-col groups ----
#pragma unroll
        for (int a = 0; a < NA; ++a) {
            const float* hb = s_h + a * 256 + seg * 4;
#pragma unroll
            for (int kl = 0; kl < 2; ++kl) {
                const int k = 2 * half + kl;   // compile-time after unroll
                float4 hv = *(const float4*)(hb + 128 * kl);
                acc[a] += hv.x * wr[k].x + hv.y * wr[k].y + hv.z * wr[k].z + hv.w * wr[k].w;
            }
        }
        __syncthreads();   // s_h reused by next half
    }

    // ---- reduce: shfl seg-reduce within wave, then cross-wave partials ----
#pragma unroll
    for (int a = 0; a < NA; ++a) {
        float v = acc[a];
        v += __shfl_xor(v, 8);
        v += __shfl_xor(v, 16);
        v += __shfl_xor(v, 32);
        if ((lane >> 3) == 0) s_part[w * (NA * NCH) + a * NCH + c] = v;
    }
    __syncthreads();

    if (t < NA * NCH)
        out[(size_t)b * (NA * NCH) + t] =
            s_part[t] + s_part[160 + t] + s_part[320 + t] + s_part[480 + t];
}

extern "C" void kernel_launch(void* const* d_in, const int* in_sizes, int n_in,
                              void* d_out, int out_size, void* d_ws, size_t ws_size,
                              hipStream_t stream) {
    const float* x    = (const float*)d_in[0];
    // d_in[1] = masks (bool) — unused; mask derived from x
    const float* lpm  = (const float*)d_in[2];
    const float* pm   = (const float*)d_in[3];
    const float* stdp = (const float*)d_in[4];
    const float* w0   = (const float*)d_in[5];
    const float* wsg  = (const float*)d_in[6];
    float* out = (float*)d_out;

    const int B = in_sizes[0] / (LSEQ * NA);  // 1024

    float* vtn = (float*)d_ws;                 // 400 floats (pad to 1024)
    float* wfb = (float*)d_ws + 1024;          // 8*512 floats

    wf_vt_kernel<<<dim3(NCH + 1), dim3(256), 0, stream>>>(w0, wsg, lpm, pm, wfb, vtn);
    main_kernel<<<dim3(B), dim3(256), 0, stream>>>(x, vtn, stdp, wfb, out);
}

// Round 4
// 111.111 us; speedup vs baseline: 1.7792x; 1.7792x over previous
//
#include <hip/hip_runtime.h>
#include <math.h>

#define LSEQ 512
#define NA 20
#define NCH 8

// ---------------------------------------------------------------------------
// wf_vt_kernel (adjoint formulation): the 9-layer conv3(pad1)+avgpool2 pyramid
// is a linear map A: R^512 -> R^8.  Row r of A (= Wf[r][:]) is computed by ONE
// adjoint pass from e_r: repeatedly unpool (gz[k] = 0.5*g[k>>1]) and transposed
// 3-tap conv, lengths 1 -> 2 -> ... -> 256 -> 512.  ~0.9 MFLOP total.
//   backward step (input len P, weights w[co][ci][0..2]):
//     out[ci][2p]   = 0.5 * sum_co( (w0+w1)*g[co][p] + w2*g[co][p-1] )
//     out[ci][2p+1] = 0.5 * sum_co( (w1+w2)*g[co][p] + w0*g[co][p+1] )
// Blocks 0..7: row r.  Block 8: vtn (400 entries).  wf layout: [c][s], stride 512.
// ---------------------------------------------------------------------------
__global__ __launch_bounds__(256) void wf_vt_kernel(
    const float* __restrict__ w0,   // [8*3]
    const float* __restrict__ wsg,  // [8*8*8*3]  ws[li][co][ci][j]
    const float* __restrict__ lpm,
    const float* __restrict__ pm,
    float* __restrict__ wf,         // [8*512]
    float* __restrict__ vtn)        // [400]
{
    const int t = threadIdx.x;

    if (blockIdx.x == NCH) {
        for (int o = t; o < NA * NA; o += 256) {
            int j = o / NA, a = o % NA;
            float v = 0.f;
            if (a > j && a <= NA - 2)
                v += fminf(fmaxf(lpm[j * NA + a], 0.001f), 1.0f) * pm[j * NA + a];
            if (a < j)
                v += fminf(fmaxf(lpm[a * NA + j], 0.001f), 1.0f) * pm[a * NA + j];
            vtn[o] = v;
        }
        return;
    }

    const int r = blockIdx.x;  // output channel row of Wf

    __shared__ float gA[NCH * 256];   // [co][p], stride 256
    __shared__ float gB[NCH * 256];
    __shared__ float4 s_e[NCH * NCH]; // [co][ci] -> (w0+w1, w2, w1+w2, w0)

    if (t < NCH) gA[t * 256] = (t == r) ? 1.f : 0.f;
    __syncthreads();

    int P = 1;  // current grad length (== 1 << step)
    for (int step = 0; step < 8; ++step) {
        const int li = 7 - step;  // ws layer index, backward order
        if (t < 64) {
            const int co = t >> 3, ci = t & 7;
            const float* wp = wsg + li * 192 + co * 24 + ci * 3;
            const float a0 = wp[0], a1 = wp[1], a2 = wp[2];
            s_e[co * 8 + ci] = make_float4(a0 + a1, a2, a1 + a2, a0);
        }
        __syncthreads();
        const float* gi = (step & 1) ? gB : gA;
        float* go = (step & 1) ? gA : gB;
        for (int it = t; it < NCH * P; it += 256) {
            const int ci = it >> step;     // P == 1<<step
            const int p = it & (P - 1);
            float accE = 0.f, accO = 0.f;
#pragma unroll
            for (int co = 0; co < NCH; ++co) {
                const float g0 = gi[co * 256 + p];
                const float gm = (p > 0) ? gi[co * 256 + p - 1] : 0.f;
                const float gp = (p + 1 < P) ? gi[co * 256 + p + 1] : 0.f;
                const float4 e = s_e[co * 8 + ci];
                accE += e.x * g0 + e.y * gm;
                accO += e.z * g0 + e.w * gp;
            }
            *(float2*)(go + ci * 256 + 2 * p) = make_float2(0.5f * accE, 0.5f * accO);
        }
        __syncthreads();
        P <<= 1;
    }

    // P == 256; final state sits in gA.  Backward through layer 0 -> wf row r.
    {
        const int p = t;  // 0..255, produces output positions 2p, 2p+1
        float accE = 0.f, accO = 0.f;
#pragma unroll
        for (int co = 0; co < NCH; ++co) {
            const float g0 = gA[co * 256 + p];
            const float gm = (p > 0) ? gA[co * 256 + p - 1] : 0.f;
            const float gp = (p < 255) ? gA[co * 256 + p + 1] : 0.f;
            const float q0 = w0[co * 3 + 0], q1 = w0[co * 3 + 1], q2 = w0[co * 3 + 2];
            accE += (q0 + q1) * g0 + q2 * gm;
            accO += (q1 + q2) * g0 + q0 * gp;
        }
        *(float2*)(wf + r * 512 + 2 * p) = make_float2(0.5f * accE, 0.5f * accO);
    }
}

// ---------------------------------------------------------------------------
// main_kernel: one block per b.  No LDS atomics anywhere.
// Half-split column space: s_h is [20][256] -> total LDS 25.2 KB -> 4
// blocks/CU (grid is exactly 4/CU).
// R4 fix (scratch-spill post-mortem of R2/R3): NO register arrays at all.
//   - R2/R3 spilled ~830B/thread to scratch (WRITE_SIZE 219MB, 114us): the
//     fully-unrolled 40-iter phase-2 batched ds_reads past the 128-VGPR cap
//     and demoted acc[20]/wr[4] to scratch.
//   - phase 2 is now R1's proven low-pressure shape: '#pragma unroll 1' over
//     a, SCALAR acc, 2 ds_read_b128, immediate shfl seg-reduce, accumulate
//     into s_part (+=, slot owned by one thread across halves).
//   - wr0..wr3 are named float4 scalars; per-half pair picked by a select
//     that folds at compile time (and is cndmask, never scratch, if not).
// ---------------------------------------------------------------------------
__global__ __launch_bounds__(256, 4) void main_kernel(
    const float* __restrict__ x,      // [B,L,A]
    const float* __restrict__ vtn,    // [400]
    const float* __restrict__ g_std,  // [1]
    const float* __restrict__ wf,     // [8*512]
    float* __restrict__ out)          // [B*160]
{
    const int b = blockIdx.x;
    const int t = threadIdx.x;
    const int c = t & 7;       // channel
    const int seg = t >> 3;    // 0..31: owns s = seg*4 + 128k + i
    const int w = t >> 6;
    const int lane = t & 63;

    __shared__ __align__(16) float s_h[NA * 256];   // 20480B
    __shared__ __align__(16) float s_vtn[NA * NA];  // 1600B
    __shared__ float s_part[4 * NA * NCH];          // 2560B
    __shared__ unsigned char s_idx[LSEQ];           // 512B

    // ---- phase 0: weights -> registers, vtn -> LDS, idx from global ----
    const float* wbase = wf + c * 512 + seg * 4;
    const float4 wr0 = *(const float4*)(wbase + 0);
    const float4 wr1 = *(const float4*)(wbase + 128);
    const float4 wr2 = *(const float4*)(wbase + 256);
    const float4 wr3 = *(const float4*)(wbase + 384);

    if (t < NA * NA / 4) ((float4*)s_vtn)[t] = ((const float4*)vtn)[t];

    // zero partials (accumulated across the two halves)
    for (int i = t; i < 4 * NA * NCH; i += 256) s_part[i] = 0.f;

    const float4* xb = (const float4*)(x + (size_t)b * LSEQ * NA);
#pragma unroll
    for (int rep = 0; rep < 2; ++rep) {
        int s = t + rep * 256;
        int id = 255;
#pragma unroll
        for (int q = 0; q < 5; ++q) {
            float4 v = xb[s * 5 + q];
            if (v.x > .5f) id = 4 * q + 0;
            if (v.y > .5f) id = 4 * q + 1;
            if (v.z > .5f) id = 4 * q + 2;
            if (v.w > .5f) id = 4 * q + 3;
        }
        s_idx[s] = (unsigned char)id;
    }
    __syncthreads();

    const float stdv = g_std[0];
    const float inv2s2 = 1.f / (2.f * stdv * stdv);
    const float vks[3] = {__expf(-1.f * inv2s2), __expf(-4.f * inv2s2), __expf(-9.f * inv2s2)};

#pragma unroll
    for (int half = 0; half < 2; ++half) {
        // ---- phase 1: dense h build for columns [256*half, 256*half+256) ----
        {
            const int s = 256 * half + t;   // this thread's column (global index)
            const int ai = s_idx[s];
            const bool valid = ai < NA;
#pragma unroll
            for (int a = 0; a < NA; ++a) {
                float v = valid ? (s_vtn[ai * NA + a] + (a == ai ? 1.f : 0.f)) : 0.f;
                s_h[a * 256 + t] = v;
            }
#pragma unroll
            for (int k = 1; k <= 3; ++k) {
                const float add = vks[k - 1];
                if (s == LSEQ - 1) {
                    for (int u = LSEQ - 1 - k; u <= LSEQ - 1; ++u) {
                        int tg = s_idx[u];
                        if (tg < NA)
                            s_h[tg * 256 + t] =
                                (valid ? s_vtn[ai * NA + tg] + (tg == ai ? 1.f : 0.f) : 0.f) + add;
                    }
                } else if (s >= k) {
                    int tg = s_idx[s - k];
                    if (tg < NA)
                        s_h[tg * 256 + t] =
                            (valid ? s_vtn[ai * NA + tg] + (tg == ai ? 1.f : 0.f) : 0.f) + add;
                }
                if (s == 0) {
                    for (int u = 0; u <= k; ++u) {
                        int tg = s_idx[u];
                        if (tg < NA)
                            s_h[tg * 256 + t] =
                                (valid ? s_vtn[ai * NA + tg] + (tg == ai ? 1.f : 0.f) : 0.f) + add;
                    }
                } else if (s + k < LSEQ) {
                    int tg = s_idx[s + k];
                    if (tg < NA)
                        s_h[tg * 256 + t] =
                            (valid ? s_vtn[ai * NA + tg] + (tg == ai ? 1.f : 0.f) : 0.f) + add;
                }
            }
        }
        __syncthreads();

        // ---- phase 2: this half's two 128-col groups, low register pressure ----
        const float4 wA = half ? wr2 : wr0;   // folds after unroll
        const float4 wB = half ? wr3 : wr1;
#pragma unroll 1
        for (int a = 0; a < NA; ++a) {
            const float* hb = s_h + a * 256 + seg * 4;
            float4 h0 = *(const float4*)(hb);
            float4 h1 = *(const float4*)(hb + 128);
            float acc = h0.x * wA.x + h0.y * wA.y + h0.z * wA.z + h0.w * wA.w
                      + h1.x * wB.x + h1.y * wB.y + h1.z * wB.z + h1.w * wB.w;
            acc += __shfl_xor(acc, 8);
            acc += __shfl_xor(acc, 16);
            acc += __shfl_xor(acc, 32);
            if ((lane >> 3) == 0) s_part[w * (NA * NCH) + a * NCH + c] += acc;
        }
        __syncthreads();   // s_h reused by next half / s_part ready after last
    }

    if (t < NA * NCH)
        out[(size_t)b * (NA * NCH) + t] =
            s_part[t] + s_part[160 + t] + s_part[320 + t] + s_part[480 + t];
}

extern "C" void kernel_launch(void* const* d_in, const int* in_sizes, int n_in,
                              void* d_out, int out_size, void* d_ws, size_t ws_size,
                              hipStream_t stream) {
    const float* x    = (const float*)d_in[0];
    // d_in[1] = masks (bool) — unused; mask derived from x
    const float* lpm  = (const float*)d_in[2];
    const float* pm   = (const float*)d_in[3];
    const float* stdp = (const float*)d_in[4];
    const float* w0   = (const float*)d_in[5];
    const float* wsg  = (const float*)d_in[6];
    float* out = (float*)d_out;

    const int B = in_sizes[0] / (LSEQ * NA);  // 1024

    float* vtn = (float*)d_ws;                 // 400 floats (pad to 1024)
    float* wfb = (float*)d_ws + 1024;          // 8*512 floats

    wf_vt_kernel<<<dim3(NCH + 1), dim3(256), 0, stream>>>(w0, wsg, lpm, pm, wfb, vtn);
    main_kernel<<<dim3(B), dim3(256), 0, stream>>>(x, vtn, stdp, wfb, out);
}